// Round 6
// baseline (246.427 us; speedup 1.0000x reference)
//
#include <hip/hip_runtime.h>
#include <stdint.h>

#define B_ROWS 4096
#define D_DIM  512
#define N_TOT  8192
#define TEMP_INV 2.0f   // 1/0.5
#define NB     64       // N_TOT / 128 tiles per dim
#define NTRI   2080     // NB*(NB+1)/2

typedef __bf16 bf16x8 __attribute__((ext_vector_type(8)));
typedef float  f32x4  __attribute__((ext_vector_type(4)));
typedef unsigned short ushort8 __attribute__((ext_vector_type(8)));

__device__ __forceinline__ unsigned short f2bf(float f) {
    union { float f; unsigned int u; } c; c.f = f;
    unsigned int u = c.u;
    return (unsigned short)((u + 0x7fffu + ((u >> 16) & 1u)) >> 16);
}

// async global->LDS, 16B per lane. LDS dest is wave-uniform base + lane*16.
__device__ __forceinline__ void gl_lds16(const void* g, void* l) {
    __builtin_amdgcn_global_load_lds(
        (__attribute__((address_space(1))) void*)(uintptr_t)g,
        (__attribute__((address_space(3))) void*)(uintptr_t)l,
        16, 0, 0);
}

// ------- kernel 1: fused L2-normalize (write bf16 z) + positive-pair dot -------
// one wave per pair k; also zeroes rowsum and the completion counter
__global__ __launch_bounds__(256) void normpos_kernel(
    const float* __restrict__ xi, const float* __restrict__ xj,
    unsigned short* __restrict__ z, float* __restrict__ pos,
    float* __restrict__ rowsum, int* __restrict__ done) {
    if (blockIdx.x < N_TOT / 256) rowsum[blockIdx.x * 256 + threadIdx.x] = 0.f;
    if (blockIdx.x == 0 && threadIdx.x == 0) *done = 0;
    const int wid  = threadIdx.x >> 6;
    const int lane = threadIdx.x & 63;
    const int k    = blockIdx.x * 4 + wid;
    const float4* a4 = (const float4*)(xi + (size_t)k * D_DIM);
    const float4* b4 = (const float4*)(xj + (size_t)k * D_DIM);
    float4 va0 = a4[2 * lane], va1 = a4[2 * lane + 1];
    float4 vb0 = b4[2 * lane], vb1 = b4[2 * lane + 1];
    float ssa = va0.x*va0.x + va0.y*va0.y + va0.z*va0.z + va0.w*va0.w
              + va1.x*va1.x + va1.y*va1.y + va1.z*va1.z + va1.w*va1.w;
    float ssb = vb0.x*vb0.x + vb0.y*vb0.y + vb0.z*vb0.z + vb0.w*vb0.w
              + vb1.x*vb1.x + vb1.y*vb1.y + vb1.z*vb1.z + vb1.w*vb1.w;
    float dot = va0.x*vb0.x + va0.y*vb0.y + va0.z*vb0.z + va0.w*vb0.w
              + va1.x*vb1.x + va1.y*vb1.y + va1.z*vb1.z + va1.w*vb1.w;
    #pragma unroll
    for (int m = 32; m >= 1; m >>= 1) {
        ssa += __shfl_xor(ssa, m);
        ssb += __shfl_xor(ssb, m);
        dot += __shfl_xor(dot, m);
    }
    const float rna = 1.0f / fmaxf(sqrtf(ssa), 1e-12f);
    const float rnb = 1.0f / fmaxf(sqrtf(ssb), 1e-12f);
    float av[8] = {va0.x, va0.y, va0.z, va0.w, va1.x, va1.y, va1.z, va1.w};
    float bv[8] = {vb0.x, vb0.y, vb0.z, vb0.w, vb1.x, vb1.y, vb1.z, vb1.w};
    union { ushort8 v; unsigned short s[8]; } oa, ob;
    #pragma unroll
    for (int i = 0; i < 8; ++i) {
        oa.s[i] = f2bf(av[i] * rna);
        ob.s[i] = f2bf(bv[i] * rnb);
    }
    *(ushort8*)(z + (size_t)k * D_DIM + lane * 8) = oa.v;
    *(ushort8*)(z + (size_t)(k + B_ROWS) * D_DIM + lane * 8) = ob.v;
    if (lane == 0) pos[k] = dot * rna * rnb;
}

// -------- kernel 2: symmetric fused Gram-row-sum (v0 body, best measured 61.5us)
// + fused finalize tail: the last block to retire (device-scope completion counter
// after __threadfence) computes the scalar loss in-place, eliminating the third
// dispatch and its launch gap. rowsum is read back via atomicAdd(p, 0.0f) for
// cross-XCD coherence.
__global__ __launch_bounds__(256) void simrow_kernel(
    const unsigned short* __restrict__ z, float* __restrict__ rowsum,
    const float* __restrict__ pos, float* __restrict__ out,
    int* __restrict__ done) {
    __shared__ unsigned short As[128 * 32];  // 8 KB
    __shared__ unsigned short Bs[128 * 32];  // 8 KB
    __shared__ float rsum[128];
    __shared__ float csum[128];
    const int tid  = threadIdx.x;
    const int lane = tid & 63;
    const int wid  = tid >> 6;

    // map linear block id -> upper-triangular (bi, bj), bi <= bj
    const int t0 = blockIdx.x;
    int bi = (int)(NB + 0.5f - sqrtf((NB + 0.5f) * (NB + 0.5f) - 2.0f * t0));
    if (bi < 0) bi = 0;
    if (bi > NB - 1) bi = NB - 1;
    // start(bi) = bi*NB - bi*(bi-1)/2
    while (bi > 0 && (bi * NB - bi * (bi - 1) / 2) > t0) --bi;
    while ((bi + 1) * NB - (bi + 1) * bi / 2 <= t0) ++bi;
    const int bj = bi + (t0 - (bi * NB - bi * (bi - 1) / 2));
    const int row0 = bi * 128;
    const int col0 = bj * 128;
    const bool diag = (bi == bj);

    if (tid < 128) { rsum[tid] = 0.f; csum[tid] = 0.f; }

    const int wr = wid >> 1, wc = wid & 1;
    f32x4 acc[4][4] = {};

    // staging: lane -> (row = wid*16 + (lane>>2), slot = lane&3)
    // slot c stores global k-chunk c ^ ((row>>1)&3); here (row>>1)&3 == (lane>>3)&3
    const int srow = wid * 16 + (lane >> 2);
    const int skc  = ((lane & 3) ^ ((lane >> 3) & 3)) * 8;

    for (int kt = 0; kt < D_DIM / 32; ++kt) {
        const int k0 = kt * 32;
        #pragma unroll
        for (int t = 0; t < 2; ++t) {
            const int r = t * 64 + srow;
            gl_lds16(z + (size_t)(row0 + r) * D_DIM + k0 + skc,
                     &As[t * 2048 + wid * 512]);
            if (!diag)
                gl_lds16(z + (size_t)(col0 + r) * D_DIM + k0 + skc,
                         &Bs[t * 2048 + wid * 512]);
        }
        __syncthreads();
        const unsigned short* Bsrc = diag ? As : Bs;
        const int kqi = lane >> 4;         // desired global k-chunk
        const int ml  = lane & 15;
        const int sw  = (ml >> 1) & 3;     // swizzle term for this row parity
        const int slot = (kqi ^ sw) * 8;
        bf16x8 af[4], bfr[4];
        #pragma unroll
        for (int mi = 0; mi < 4; ++mi)
            af[mi] = *(const bf16x8*)&As[(wr * 64 + mi * 16 + ml) * 32 + slot];
        #pragma unroll
        for (int ni = 0; ni < 4; ++ni)
            bfr[ni] = *(const bf16x8*)&Bsrc[(wc * 64 + ni * 16 + ml) * 32 + slot];
        #pragma unroll
        for (int mi = 0; mi < 4; ++mi)
            #pragma unroll
            for (int ni = 0; ni < 4; ++ni)
                acc[mi][ni] = __builtin_amdgcn_mfma_f32_16x16x32_bf16(
                    af[mi], bfr[ni], acc[mi][ni], 0, 0, 0);
        __syncthreads();
    }

    // epilogue: e = exp(2*sim), mask diagonal; row sums always, col sums if off-diag
    const int quad = lane >> 4;
    const int cl   = lane & 15;
    float colacc[4] = {0.f, 0.f, 0.f, 0.f};
    #pragma unroll
    for (int mi = 0; mi < 4; ++mi) {
        #pragma unroll
        for (int r = 0; r < 4; ++r) {
            const int lrow = wr * 64 + mi * 16 + quad * 4 + r;
            const int irow = row0 + lrow;
            float s = 0.f;
            #pragma unroll
            for (int ni = 0; ni < 4; ++ni) {
                const int jcol = col0 + wc * 64 + ni * 16 + cl;
                float e = __expf(TEMP_INV * acc[mi][ni][r]);
                e = (irow == jcol) ? 0.f : e;
                s += e;
                colacc[ni] += e;
            }
            s += __shfl_xor(s, 1);
            s += __shfl_xor(s, 2);
            s += __shfl_xor(s, 4);
            s += __shfl_xor(s, 8);
            if (cl == 0) atomicAdd(&rsum[lrow], s);
        }
    }
    if (!diag) {
        #pragma unroll
        for (int ni = 0; ni < 4; ++ni) {
            float c = colacc[ni];
            c += __shfl_xor(c, 16);
            c += __shfl_xor(c, 32);
            if (quad == 0) atomicAdd(&csum[wc * 64 + ni * 16 + cl], c);
        }
    }
    __syncthreads();
    if (tid < 128) {
        atomicAdd(&rowsum[row0 + tid], rsum[tid]);
        if (!diag) atomicAdd(&rowsum[col0 + tid], csum[tid]);
    }

    // ---- fused finalize: last block to retire computes the scalar loss ----
    __threadfence();              // release: rowsum atomics ordered before counter
    __shared__ int amlast;
    if (tid == 0) {
        int old = atomicAdd(done, 1);   // device-scope
        amlast = (old == NTRI - 1);
    }
    __syncthreads();
    if (amlast) {
        // all 2080 counter increments observed => all blocks' fences executed =>
        // all rowsum atomics complete. Read via atomicAdd(p,0) for coherence.
        float s = 0.f;
        for (int i = tid; i < N_TOT; i += 256)
            s += logf(atomicAdd(&rowsum[i], 0.0f));
        float p = 0.f;
        for (int i = tid; i < B_ROWS; i += 256) p += pos[i];
        #pragma unroll
        for (int m = 32; m >= 1; m >>= 1) {
            s += __shfl_xor(s, m);
            p += __shfl_xor(p, m);
        }
        __shared__ float ws[4], wp[4];
        if ((tid & 63) == 0) { ws[tid >> 6] = s; wp[tid >> 6] = p; }
        __syncthreads();
        if (tid == 0) {
            float tot = ws[0] + ws[1] + ws[2] + ws[3];
            float ptot = wp[0] + wp[1] + wp[2] + wp[3];
            // loss = mean(log denom) - (2*posSum)/(temp*N)
            out[0] = tot / (float)N_TOT - ptot * (2.0f * TEMP_INV / (float)N_TOT);
        }
    }
}

extern "C" void kernel_launch(void* const* d_in, const int* in_sizes, int n_in,
                              void* d_out, int out_size, void* d_ws, size_t ws_size,
                              hipStream_t stream) {
    const float* xi = (const float*)d_in[0];
    const float* xj = (const float*)d_in[1];
    float* out = (float*)d_out;
    char* ws = (char*)d_ws;

    unsigned short* z = (unsigned short*)ws;                       // 8 MB bf16
    float* rowsum = (float*)(ws + (size_t)N_TOT * D_DIM * 2);      // 32 KB
    float* pos = rowsum + N_TOT;                                   // 16 KB
    int* done = (int*)(pos + B_ROWS);                              // 4 B

    normpos_kernel<<<B_ROWS / 4, 256, 0, stream>>>(xi, xj, z, pos, rowsum, done);
    simrow_kernel<<<NTRI, 256, 0, stream>>>(z, rowsum, pos, out, done);
}

// Round 7
// 140.866 us; speedup vs baseline: 1.7494x; 1.7494x over previous
//
#include <hip/hip_runtime.h>
#include <stdint.h>

#define B_ROWS 4096
#define D_DIM  512
#define N_TOT  8192
#define TEMP_INV 2.0f   // 1/0.5
#define NB     64       // N_TOT / 128 tiles per dim
#define NTRI   2080     // NB*(NB+1)/2
#define BK     64
#define KT_N   (D_DIM / BK)  // 8 K-steps

typedef __bf16 bf16x8 __attribute__((ext_vector_type(8)));
typedef float  f32x4  __attribute__((ext_vector_type(4)));
typedef unsigned short ushort8 __attribute__((ext_vector_type(8)));

__device__ __forceinline__ unsigned short f2bf(float f) {
    union { float f; unsigned int u; } c; c.f = f;
    unsigned int u = c.u;
    return (unsigned short)((u + 0x7fffu + ((u >> 16) & 1u)) >> 16);
}

// async global->LDS, 16B per lane. LDS dest is wave-uniform base + lane*16;
// global source is per-lane (carries the swizzle).
__device__ __forceinline__ void gl_lds16(const void* g, void* l) {
    __builtin_amdgcn_global_load_lds(
        (__attribute__((address_space(1))) void*)(uintptr_t)g,
        (__attribute__((address_space(3))) void*)(uintptr_t)l,
        16, 0, 0);
}

// ------- kernel 1: fused L2-normalize (write bf16 z) + positive-pair dot -------
// one wave per pair k; also zeroes rowsum (replaces hipMemsetAsync dispatch)
__global__ __launch_bounds__(256) void normpos_kernel(
    const float* __restrict__ xi, const float* __restrict__ xj,
    unsigned short* __restrict__ z, float* __restrict__ pos,
    float* __restrict__ rowsum) {
    if (blockIdx.x < N_TOT / 256) rowsum[blockIdx.x * 256 + threadIdx.x] = 0.f;
    const int wid  = threadIdx.x >> 6;
    const int lane = threadIdx.x & 63;
    const int k    = blockIdx.x * 4 + wid;
    const float4* a4 = (const float4*)(xi + (size_t)k * D_DIM);
    const float4* b4 = (const float4*)(xj + (size_t)k * D_DIM);
    float4 va0 = a4[2 * lane], va1 = a4[2 * lane + 1];
    float4 vb0 = b4[2 * lane], vb1 = b4[2 * lane + 1];
    float ssa = va0.x*va0.x + va0.y*va0.y + va0.z*va0.z + va0.w*va0.w
              + va1.x*va1.x + va1.y*va1.y + va1.z*va1.z + va1.w*va1.w;
    float ssb = vb0.x*vb0.x + vb0.y*vb0.y + vb0.z*vb0.z + vb0.w*vb0.w
              + vb1.x*vb1.x + vb1.y*vb1.y + vb1.z*vb1.z + vb1.w*vb1.w;
    float dot = va0.x*vb0.x + va0.y*vb0.y + va0.z*vb0.z + va0.w*vb0.w
              + va1.x*vb1.x + va1.y*vb1.y + va1.z*vb1.z + va1.w*vb1.w;
    #pragma unroll
    for (int m = 32; m >= 1; m >>= 1) {
        ssa += __shfl_xor(ssa, m);
        ssb += __shfl_xor(ssb, m);
        dot += __shfl_xor(dot, m);
    }
    const float rna = 1.0f / fmaxf(sqrtf(ssa), 1e-12f);
    const float rnb = 1.0f / fmaxf(sqrtf(ssb), 1e-12f);
    float av[8] = {va0.x, va0.y, va0.z, va0.w, va1.x, va1.y, va1.z, va1.w};
    float bv[8] = {vb0.x, vb0.y, vb0.z, vb0.w, vb1.x, vb1.y, vb1.z, vb1.w};
    union { ushort8 v; unsigned short s[8]; } oa, ob;
    #pragma unroll
    for (int i = 0; i < 8; ++i) {
        oa.s[i] = f2bf(av[i] * rna);
        ob.s[i] = f2bf(bv[i] * rnb);
    }
    *(ushort8*)(z + (size_t)k * D_DIM + lane * 8) = oa.v;
    *(ushort8*)(z + (size_t)(k + B_ROWS) * D_DIM + lane * 8) = ob.v;
    if (lane == 0) pos[k] = dot * rna * rnb;
}

// -------- kernel 2: symmetric fused Gram-row-sum over upper-triangular tiles --------
// v7 = v0 structure with BK=64: 8 stage->sync->compute->sync rounds instead of 16,
// 32 MFMA per barrier pair instead of 16. Halves the structural stage+drain+barrier
// overhead (the 2-phase skeleton, ~70% of v0's time per m233-style analysis) at
// unchanged occupancy (LDS 33KB -> >=4 blocks/CU; VGPR ~80).
// 8-slot XOR swizzle (generalizes v0's proven 4-slot one): physical slot p at row R
// holds global k-chunk p ^ ((R>>1)&7); applied on BOTH stage-source and read sides.
__global__ __launch_bounds__(256) void simrow_kernel(
    const unsigned short* __restrict__ z, float* __restrict__ rowsum) {
    __shared__ unsigned short As[128 * BK];  // 16 KB
    __shared__ unsigned short Bs[128 * BK];  // 16 KB
    __shared__ float rsum[128];
    __shared__ float csum[128];
    const int tid  = threadIdx.x;
    const int lane = tid & 63;
    const int wid  = tid >> 6;

    // map linear block id -> upper-triangular (bi, bj), bi <= bj
    const int t0 = blockIdx.x;
    int bi = (int)(NB + 0.5f - sqrtf((NB + 0.5f) * (NB + 0.5f) - 2.0f * t0));
    if (bi < 0) bi = 0;
    if (bi > NB - 1) bi = NB - 1;
    while (bi > 0 && (bi * NB - bi * (bi - 1) / 2) > t0) --bi;
    while ((bi + 1) * NB - (bi + 1) * bi / 2 <= t0) ++bi;
    const int bj = bi + (t0 - (bi * NB - bi * (bi - 1) / 2));
    const int row0 = bi * 128;
    const int col0 = bj * 128;
    const bool diag = (bi == bj);

    if (tid < 128) { rsum[tid] = 0.f; csum[tid] = 0.f; }

    const int wr = wid >> 1, wc = wid & 1;
    f32x4 acc[4][4] = {};

    // ---- staging geometry: per gl_lds, 64 lanes fill 8 rows x 128B.
    // lane -> row-in-8 = lane>>3, physical chunk = lane&7.
    // wave wid stages rows [wid*32, wid*32+32) via g=0..3 (8 rows each).
    // source chunk = (lane&7) ^ sw,  sw = ((g*8 + lane>>3)>>1)&7 = (g*4 + (lane>>4))&7
    const int srow8 = lane >> 3;
    const int spos  = lane & 7;

    const int kqi = lane >> 4;         // k-quarter within a 32-wide MFMA step
    const int ml  = lane & 15;
    const int sw8 = (ml >> 1) & 7;     // read-side swizzle: ((R>>1)&7) with R=...+ml
    const int slot0 = ((0 + kqi) ^ sw8) * 8;   // kk=0: chunks 0..3
    const int slot1 = ((4 + kqi) ^ sw8) * 8;   // kk=1: chunks 4..7

    for (int kt = 0; kt < KT_N; ++kt) {
        const int k0 = kt * BK;
        #pragma unroll
        for (int g = 0; g < 4; ++g) {
            const int lr = wid * 32 + g * 8 + srow8;           // local row 0..127
            const int sc = spos ^ ((g * 4 + (lane >> 4)) & 7); // source chunk
            gl_lds16(z + (size_t)(row0 + lr) * D_DIM + k0 + sc * 8,
                     &As[(wid * 32 + g * 8) * BK]);
            if (!diag)
                gl_lds16(z + (size_t)(col0 + lr) * D_DIM + k0 + sc * 8,
                         &Bs[(wid * 32 + g * 8) * BK]);
        }
        __syncthreads();
        const unsigned short* Bsrc = diag ? As : Bs;
        bf16x8 af[4], bfr[4];
        // ---- kk = 0 ----
        #pragma unroll
        for (int mi = 0; mi < 4; ++mi)
            af[mi] = *(const bf16x8*)&As[(wr * 64 + mi * 16 + ml) * BK + slot0];
        #pragma unroll
        for (int ni = 0; ni < 4; ++ni)
            bfr[ni] = *(const bf16x8*)&Bsrc[(wc * 64 + ni * 16 + ml) * BK + slot0];
        #pragma unroll
        for (int mi = 0; mi < 4; ++mi)
            #pragma unroll
            for (int ni = 0; ni < 4; ++ni)
                acc[mi][ni] = __builtin_amdgcn_mfma_f32_16x16x32_bf16(
                    af[mi], bfr[ni], acc[mi][ni], 0, 0, 0);
        // ---- kk = 1 ----
        #pragma unroll
        for (int mi = 0; mi < 4; ++mi)
            af[mi] = *(const bf16x8*)&As[(wr * 64 + mi * 16 + ml) * BK + slot1];
        #pragma unroll
        for (int ni = 0; ni < 4; ++ni)
            bfr[ni] = *(const bf16x8*)&Bsrc[(wc * 64 + ni * 16 + ml) * BK + slot1];
        #pragma unroll
        for (int mi = 0; mi < 4; ++mi)
            #pragma unroll
            for (int ni = 0; ni < 4; ++ni)
                acc[mi][ni] = __builtin_amdgcn_mfma_f32_16x16x32_bf16(
                    af[mi], bfr[ni], acc[mi][ni], 0, 0, 0);
        __syncthreads();
    }

    // epilogue: e = exp(2*sim), mask diagonal; row sums always, col sums if off-diag
    const int quad = lane >> 4;
    const int cl   = lane & 15;
    float colacc[4] = {0.f, 0.f, 0.f, 0.f};
    #pragma unroll
    for (int mi = 0; mi < 4; ++mi) {
        #pragma unroll
        for (int r = 0; r < 4; ++r) {
            const int lrow = wr * 64 + mi * 16 + quad * 4 + r;
            const int irow = row0 + lrow;
            float s = 0.f;
            #pragma unroll
            for (int ni = 0; ni < 4; ++ni) {
                const int jcol = col0 + wc * 64 + ni * 16 + cl;
                float e = __expf(TEMP_INV * acc[mi][ni][r]);
                e = (irow == jcol) ? 0.f : e;
                s += e;
                colacc[ni] += e;
            }
            s += __shfl_xor(s, 1);
            s += __shfl_xor(s, 2);
            s += __shfl_xor(s, 4);
            s += __shfl_xor(s, 8);
            if (cl == 0) atomicAdd(&rsum[lrow], s);
        }
    }
    if (!diag) {
        #pragma unroll
        for (int ni = 0; ni < 4; ++ni) {
            float c = colacc[ni];
            c += __shfl_xor(c, 16);
            c += __shfl_xor(c, 32);
            if (quad == 0) atomicAdd(&csum[wc * 64 + ni * 16 + cl], c);
        }
    }
    __syncthreads();
    if (tid < 128) {
        atomicAdd(&rowsum[row0 + tid], rsum[tid]);
        if (!diag) atomicAdd(&rowsum[col0 + tid], csum[tid]);
    }
}

// ---------------- kernel 3: finalize scalar loss ----------------
__global__ __launch_bounds__(256) void finalize_kernel(
    const float* __restrict__ rowsum, const float* __restrict__ pos,
    float* __restrict__ out) {
    const int t = threadIdx.x;
    float s = 0.f;
    for (int i = t; i < N_TOT; i += 256) s += logf(rowsum[i]);
    float p = 0.f;
    for (int i = t; i < B_ROWS; i += 256) p += pos[i];
    #pragma unroll
    for (int m = 32; m >= 1; m >>= 1) {
        s += __shfl_xor(s, m);
        p += __shfl_xor(p, m);
    }
    __shared__ float ws[4], wp[4];
    if ((t & 63) == 0) { ws[t >> 6] = s; wp[t >> 6] = p; }
    __syncthreads();
    if (t == 0) {
        float tot = ws[0] + ws[1] + ws[2] + ws[3];
        float ptot = wp[0] + wp[1] + wp[2] + wp[3];
        // loss = mean(log denom) - (2*posSum)/(temp*N)
        out[0] = tot / (float)N_TOT - ptot * (2.0f * TEMP_INV / (float)N_TOT);
    }
}

extern "C" void kernel_launch(void* const* d_in, const int* in_sizes, int n_in,
                              void* d_out, int out_size, void* d_ws, size_t ws_size,
                              hipStream_t stream) {
    const float* xi = (const float*)d_in[0];
    const float* xj = (const float*)d_in[1];
    float* out = (float*)d_out;
    char* ws = (char*)d_ws;

    unsigned short* z = (unsigned short*)ws;                       // 8 MB bf16
    float* rowsum = (float*)(ws + (size_t)N_TOT * D_DIM * 2);      // 32 KB
    float* pos = rowsum + N_TOT;                                   // 16 KB

    normpos_kernel<<<B_ROWS / 4, 256, 0, stream>>>(xi, xj, z, pos, rowsum);
    simrow_kernel<<<NTRI, 256, 0, stream>>>(z, rowsum);
    finalize_kernel<<<1, 256, 0, stream>>>(rowsum, pos, out);
}

// Round 8
// 136.858 us; speedup vs baseline: 1.8006x; 1.0293x over previous
//
#include <hip/hip_runtime.h>
#include <stdint.h>

#define B_ROWS 4096
#define D_DIM  512
#define N_TOT  8192
#define TEMP_INV 2.0f   // 1/0.5
#define NB     64       // N_TOT / 128 tiles per dim
#define NTRI   2080     // NB*(NB+1)/2

typedef __bf16 bf16x8 __attribute__((ext_vector_type(8)));
typedef float  f32x4  __attribute__((ext_vector_type(4)));
typedef unsigned short ushort8 __attribute__((ext_vector_type(8)));

__device__ __forceinline__ unsigned short f2bf(float f) {
    union { float f; unsigned int u; } c; c.f = f;
    unsigned int u = c.u;
    return (unsigned short)((u + 0x7fffu + ((u >> 16) & 1u)) >> 16);
}

// async global->LDS, 16B per lane. LDS dest is wave-uniform base + lane*16;
// global source is per-lane (carries the swizzle).
__device__ __forceinline__ void gl_lds16(const void* g, void* l) {
    __builtin_amdgcn_global_load_lds(
        (__attribute__((address_space(1))) void*)(uintptr_t)g,
        (__attribute__((address_space(3))) void*)(uintptr_t)l,
        16, 0, 0);
}

// ------- kernel 1: fused L2-normalize (write bf16 z) + positive-pair dot -------
// one wave per pair k; also zeroes rowsum (replaces hipMemsetAsync dispatch)
__global__ __launch_bounds__(256) void normpos_kernel(
    const float* __restrict__ xi, const float* __restrict__ xj,
    unsigned short* __restrict__ z, float* __restrict__ pos,
    float* __restrict__ rowsum) {
    if (blockIdx.x < N_TOT / 256) rowsum[blockIdx.x * 256 + threadIdx.x] = 0.f;
    const int wid  = threadIdx.x >> 6;
    const int lane = threadIdx.x & 63;
    const int k    = blockIdx.x * 4 + wid;
    const float4* a4 = (const float4*)(xi + (size_t)k * D_DIM);
    const float4* b4 = (const float4*)(xj + (size_t)k * D_DIM);
    float4 va0 = a4[2 * lane], va1 = a4[2 * lane + 1];
    float4 vb0 = b4[2 * lane], vb1 = b4[2 * lane + 1];
    float ssa = va0.x*va0.x + va0.y*va0.y + va0.z*va0.z + va0.w*va0.w
              + va1.x*va1.x + va1.y*va1.y + va1.z*va1.z + va1.w*va1.w;
    float ssb = vb0.x*vb0.x + vb0.y*vb0.y + vb0.z*vb0.z + vb0.w*vb0.w
              + vb1.x*vb1.x + vb1.y*vb1.y + vb1.z*vb1.z + vb1.w*vb1.w;
    float dot = va0.x*vb0.x + va0.y*vb0.y + va0.z*vb0.z + va0.w*vb0.w
              + va1.x*vb1.x + va1.y*vb1.y + va1.z*vb1.z + va1.w*vb1.w;
    #pragma unroll
    for (int m = 32; m >= 1; m >>= 1) {
        ssa += __shfl_xor(ssa, m);
        ssb += __shfl_xor(ssb, m);
        dot += __shfl_xor(dot, m);
    }
    const float rna = 1.0f / fmaxf(sqrtf(ssa), 1e-12f);
    const float rnb = 1.0f / fmaxf(sqrtf(ssb), 1e-12f);
    float av[8] = {va0.x, va0.y, va0.z, va0.w, va1.x, va1.y, va1.z, va1.w};
    float bv[8] = {vb0.x, vb0.y, vb0.z, vb0.w, vb1.x, vb1.y, vb1.z, vb1.w};
    union { ushort8 v; unsigned short s[8]; } oa, ob;
    #pragma unroll
    for (int i = 0; i < 8; ++i) {
        oa.s[i] = f2bf(av[i] * rna);
        ob.s[i] = f2bf(bv[i] * rnb);
    }
    *(ushort8*)(z + (size_t)k * D_DIM + lane * 8) = oa.v;
    *(ushort8*)(z + (size_t)(k + B_ROWS) * D_DIM + lane * 8) = ob.v;
    if (lane == 0) pos[k] = dot * rna * rnb;
}

// -------- kernel 2: symmetric fused Gram-row-sum over upper-triangular tiles --------
// v8 = v0's exact tile/swizzle/loop structure, re-partitioned for OCCUPANCY:
//   8 waves (512 thr) per 128x128 tile, wave grid 2x4, per-wave output 64x32
//   -> acc[4][2] = 32 AGPRs (v0: 64). Unified VGPR+AGPR ~100 <= 128-reg bracket
//   -> 4 waves/SIMD (16 waves/CU, 2 blocks/CU) vs v0's 2 waves/SIMD.
//   The kernel is latency-bound on the per-iter vmcnt(0) L3-round-trip drain
//   (74MB TCC fetch / 2080 blocks ~ one miss/iter); doubling resident waves
//   doubles the latency-hiding pool. Staging: each wave = 1 gl_lds for A
//   (+1 for B): 64 lanes x 16B = 16 rows x 64B. Same measured-0-conflict
//   XOR k-chunk swizzle as v0 on both sides.
__global__ __launch_bounds__(512, 4) void simrow_kernel(
    const unsigned short* __restrict__ z, float* __restrict__ rowsum) {
    __shared__ unsigned short As[128 * 32];  // 8 KB
    __shared__ unsigned short Bs[128 * 32];  // 8 KB
    __shared__ float rsum[128];
    __shared__ float csum[128];
    const int tid  = threadIdx.x;
    const int lane = tid & 63;
    const int wid  = tid >> 6;   // 0..7

    // map linear block id -> upper-triangular (bi, bj), bi <= bj
    const int t0 = blockIdx.x;
    int bi = (int)(NB + 0.5f - sqrtf((NB + 0.5f) * (NB + 0.5f) - 2.0f * t0));
    if (bi < 0) bi = 0;
    if (bi > NB - 1) bi = NB - 1;
    while (bi > 0 && (bi * NB - bi * (bi - 1) / 2) > t0) --bi;
    while ((bi + 1) * NB - (bi + 1) * bi / 2 <= t0) ++bi;
    const int bj = bi + (t0 - (bi * NB - bi * (bi - 1) / 2));
    const int row0 = bi * 128;
    const int col0 = bj * 128;
    const bool diag = (bi == bj);

    if (tid < 128) { rsum[tid] = 0.f; csum[tid] = 0.f; }

    const int wr = wid >> 2;    // 0..1 : 64-row band
    const int wc = wid & 3;     // 0..3 : 32-col band
    f32x4 acc[4][2] = {};

    // staging: wave wid covers rows [wid*16, wid*16+16) of the 128x32 tile.
    // lane -> row = wid*16 + (lane>>2), chunkpos = lane&3;
    // source chunk = (lane&3) ^ ((row>>1)&3) = (lane&3) ^ ((lane>>3)&3)
    const int srow = wid * 16 + (lane >> 2);
    const int skc  = ((lane & 3) ^ ((lane >> 3) & 3)) * 8;
    const unsigned short* gA = z + (size_t)(row0 + srow) * D_DIM + skc;
    const unsigned short* gB = z + (size_t)(col0 + srow) * D_DIM + skc;

    const int kqi = lane >> 4;         // desired global k-chunk
    const int ml  = lane & 15;
    const int sw  = (ml >> 1) & 3;     // swizzle term for this row parity
    const int slot = (kqi ^ sw) * 8;

    for (int kt = 0; kt < D_DIM / 32; ++kt) {
        const int k0 = kt * 32;
        gl_lds16(gA + k0, &As[(wid * 16) * 32]);
        if (!diag) gl_lds16(gB + k0, &Bs[(wid * 16) * 32]);
        __syncthreads();
        const unsigned short* Bsrc = diag ? As : Bs;
        bf16x8 af[4], bfr[2];
        #pragma unroll
        for (int mi = 0; mi < 4; ++mi)
            af[mi] = *(const bf16x8*)&As[(wr * 64 + mi * 16 + ml) * 32 + slot];
        #pragma unroll
        for (int ni = 0; ni < 2; ++ni)
            bfr[ni] = *(const bf16x8*)&Bsrc[(wc * 32 + ni * 16 + ml) * 32 + slot];
        #pragma unroll
        for (int mi = 0; mi < 4; ++mi)
            #pragma unroll
            for (int ni = 0; ni < 2; ++ni)
                acc[mi][ni] = __builtin_amdgcn_mfma_f32_16x16x32_bf16(
                    af[mi], bfr[ni], acc[mi][ni], 0, 0, 0);
        __syncthreads();
    }

    // epilogue: e = exp(2*sim), mask diagonal; row sums always, col sums if off-diag
    const int quad = lane >> 4;
    const int cl   = lane & 15;
    float colacc[2] = {0.f, 0.f};
    #pragma unroll
    for (int mi = 0; mi < 4; ++mi) {
        #pragma unroll
        for (int r = 0; r < 4; ++r) {
            const int lrow = wr * 64 + mi * 16 + quad * 4 + r;
            const int irow = row0 + lrow;
            float s = 0.f;
            #pragma unroll
            for (int ni = 0; ni < 2; ++ni) {
                const int jcol = col0 + wc * 32 + ni * 16 + cl;
                float e = __expf(TEMP_INV * acc[mi][ni][r]);
                e = (irow == jcol) ? 0.f : e;
                s += e;
                colacc[ni] += e;
            }
            s += __shfl_xor(s, 1);
            s += __shfl_xor(s, 2);
            s += __shfl_xor(s, 4);
            s += __shfl_xor(s, 8);
            if (cl == 0) atomicAdd(&rsum[lrow], s);
        }
    }
    if (!diag) {
        #pragma unroll
        for (int ni = 0; ni < 2; ++ni) {
            float c = colacc[ni];
            c += __shfl_xor(c, 16);
            c += __shfl_xor(c, 32);
            if (quad == 0) atomicAdd(&csum[wc * 32 + ni * 16 + cl], c);
        }
    }
    __syncthreads();
    if (tid < 128) {
        atomicAdd(&rowsum[row0 + tid], rsum[tid]);
        if (!diag) atomicAdd(&rowsum[col0 + tid], csum[tid]);
    }
}

// ---------------- kernel 3: finalize scalar loss ----------------
__global__ __launch_bounds__(256) void finalize_kernel(
    const float* __restrict__ rowsum, const float* __restrict__ pos,
    float* __restrict__ out) {
    const int t = threadIdx.x;
    float s = 0.f;
    for (int i = t; i < N_TOT; i += 256) s += logf(rowsum[i]);
    float p = 0.f;
    for (int i = t; i < B_ROWS; i += 256) p += pos[i];
    #pragma unroll
    for (int m = 32; m >= 1; m >>= 1) {
        s += __shfl_xor(s, m);
        p += __shfl_xor(p, m);
    }
    __shared__ float ws[4], wp[4];
    if ((t & 63) == 0) { ws[t >> 6] = s; wp[t >> 6] = p; }
    __syncthreads();
    if (t == 0) {
        float tot = ws[0] + ws[1] + ws[2] + ws[3];
        float ptot = wp[0] + wp[1] + wp[2] + wp[3];
        // loss = mean(log denom) - (2*posSum)/(temp*N)
        out[0] = tot / (float)N_TOT - ptot * (2.0f * TEMP_INV / (float)N_TOT);
    }
}

extern "C" void kernel_launch(void* const* d_in, const int* in_sizes, int n_in,
                              void* d_out, int out_size, void* d_ws, size_t ws_size,
                              hipStream_t stream) {
    const float* xi = (const float*)d_in[0];
    const float* xj = (const float*)d_in[1];
    float* out = (float*)d_out;
    char* ws = (char*)d_ws;

    unsigned short* z = (unsigned short*)ws;                       // 8 MB bf16
    float* rowsum = (float*)(ws + (size_t)N_TOT * D_DIM * 2);      // 32 KB
    float* pos = rowsum + N_TOT;                                   // 16 KB

    normpos_kernel<<<B_ROWS / 4, 256, 0, stream>>>(xi, xj, z, pos, rowsum);
    simrow_kernel<<<NTRI, 512, 0, stream>>>(z, rowsum);
    finalize_kernel<<<1, 256, 0, stream>>>(rowsum, pos, out);
}

// Round 9
// 133.537 us; speedup vs baseline: 1.8454x; 1.0249x over previous
//
#include <hip/hip_runtime.h>
#include <stdint.h>

#define B_ROWS 4096
#define D_DIM  512
#define N_TOT  8192
#define TEMP_INV 2.0f   // 1/0.5
#define NB     64       // N_TOT / 128 tiles per dim
#define NTRI   2080     // NB*(NB+1)/2
#define KT_N   (D_DIM / 32)  // 16 K-steps

typedef __bf16 bf16x8 __attribute__((ext_vector_type(8)));
typedef float  f32x4  __attribute__((ext_vector_type(4)));
typedef unsigned short ushort8 __attribute__((ext_vector_type(8)));

#define VM_WAIT(N) asm volatile("s_waitcnt vmcnt(" #N ")" ::: "memory")
#define LGKM0()    asm volatile("s_waitcnt lgkmcnt(0)" ::: "memory")
#define BAR()      do { asm volatile("" ::: "memory"); \
                        __builtin_amdgcn_s_barrier();  \
                        asm volatile("" ::: "memory"); } while (0)

__device__ __forceinline__ unsigned short f2bf(float f) {
    union { float f; unsigned int u; } c; c.f = f;
    unsigned int u = c.u;
    return (unsigned short)((u + 0x7fffu + ((u >> 16) & 1u)) >> 16);
}

// async global->LDS, 16B per lane. LDS dest is wave-uniform base + lane*16;
// global source is per-lane (carries the swizzle).
__device__ __forceinline__ void gl_lds16(const void* g, void* l) {
    __builtin_amdgcn_global_load_lds(
        (__attribute__((address_space(1))) void*)(uintptr_t)g,
        (__attribute__((address_space(3))) void*)(uintptr_t)l,
        16, 0, 0);
}

// ------- kernel 1: fused L2-normalize (write bf16 z) + positive-pair dot -------
// one wave per pair k; also zeroes rowsum (replaces hipMemsetAsync dispatch)
__global__ __launch_bounds__(256) void normpos_kernel(
    const float* __restrict__ xi, const float* __restrict__ xj,
    unsigned short* __restrict__ z, float* __restrict__ pos,
    float* __restrict__ rowsum) {
    if (blockIdx.x < N_TOT / 256) rowsum[blockIdx.x * 256 + threadIdx.x] = 0.f;
    const int wid  = threadIdx.x >> 6;
    const int lane = threadIdx.x & 63;
    const int k    = blockIdx.x * 4 + wid;
    const float4* a4 = (const float4*)(xi + (size_t)k * D_DIM);
    const float4* b4 = (const float4*)(xj + (size_t)k * D_DIM);
    float4 va0 = a4[2 * lane], va1 = a4[2 * lane + 1];
    float4 vb0 = b4[2 * lane], vb1 = b4[2 * lane + 1];
    float ssa = va0.x*va0.x + va0.y*va0.y + va0.z*va0.z + va0.w*va0.w
              + va1.x*va1.x + va1.y*va1.y + va1.z*va1.z + va1.w*va1.w;
    float ssb = vb0.x*vb0.x + vb0.y*vb0.y + vb0.z*vb0.z + vb0.w*vb0.w
              + vb1.x*vb1.x + vb1.y*vb1.y + vb1.z*vb1.z + vb1.w*vb1.w;
    float dot = va0.x*vb0.x + va0.y*vb0.y + va0.z*vb0.z + va0.w*vb0.w
              + va1.x*vb1.x + va1.y*vb1.y + va1.z*vb1.z + va1.w*vb1.w;
    #pragma unroll
    for (int m = 32; m >= 1; m >>= 1) {
        ssa += __shfl_xor(ssa, m);
        ssb += __shfl_xor(ssb, m);
        dot += __shfl_xor(dot, m);
    }
    const float rna = 1.0f / fmaxf(sqrtf(ssa), 1e-12f);
    const float rnb = 1.0f / fmaxf(sqrtf(ssb), 1e-12f);
    float av[8] = {va0.x, va0.y, va0.z, va0.w, va1.x, va1.y, va1.z, va1.w};
    float bv[8] = {vb0.x, vb0.y, vb0.z, vb0.w, vb1.x, vb1.y, vb1.z, vb1.w};
    union { ushort8 v; unsigned short s[8]; } oa, ob;
    #pragma unroll
    for (int i = 0; i < 8; ++i) {
        oa.s[i] = f2bf(av[i] * rna);
        ob.s[i] = f2bf(bv[i] * rnb);
    }
    *(ushort8*)(z + (size_t)k * D_DIM + lane * 8) = oa.v;
    *(ushort8*)(z + (size_t)(k + B_ROWS) * D_DIM + lane * 8) = ob.v;
    if (lane == 0) pos[k] = dot * rna * rnb;
}

// -------- kernel 2: symmetric fused Gram-row-sum over upper-triangular tiles --------
// v9 = v8 (8-wave 128x128 tile, acc[4][2]=32 AGPR, ~50% occupancy) + 3-deep LDS
// pipeline with COUNTED vmcnt across raw barriers.
// Insight from v0/v4/v8: the latency domain is the BLOCK (barrier-synced waves
// stall together); 2 blocks/CU in every prior variant -> the per-iter L2/L3
// round-trip at the vmcnt(0) drain was always exposed. v4 proved the counted-vmcnt
// mechanism but paid occupancy for it; v8 proved the occupancy but had no pipeline.
// v9 has both: tiles t+1, t+2 stay in flight across each barrier (VM_WAIT(4)),
// each tile gets ~2 iterations of latency cover, occupancy unchanged.
// vmcnt audit: stage = exactly 2 VMEM ops/wave (A+B; diag blocks stage B
//   redundantly from identical addresses -- col0==row0). At top of iter t a wave
//   has <=6 outstanding (tiles t,t+1,t+2); VM_WAIT(4) retires tile t's 2 ops.
//   All waves wait then BAR -> tile t fully resident for the whole block.
// WAR audit: stage of tile t+3 reuses buf t%3, issued only after LGKM0+BAR
//   confirmed all waves' ds_reads of tile t completed.
__global__ __launch_bounds__(512, 4) void simrow_kernel(
    const unsigned short* __restrict__ z, float* __restrict__ rowsum) {
    __shared__ unsigned short As[3][128 * 32];  // 3 x 8 KB
    __shared__ unsigned short Bs[3][128 * 32];  // 3 x 8 KB
    __shared__ float rsum[128];
    __shared__ float csum[128];
    const int tid  = threadIdx.x;
    const int lane = tid & 63;
    const int wid  = tid >> 6;   // 0..7

    // map linear block id -> upper-triangular (bi, bj), bi <= bj
    const int t0 = blockIdx.x;
    int bi = (int)(NB + 0.5f - sqrtf((NB + 0.5f) * (NB + 0.5f) - 2.0f * t0));
    if (bi < 0) bi = 0;
    if (bi > NB - 1) bi = NB - 1;
    while (bi > 0 && (bi * NB - bi * (bi - 1) / 2) > t0) --bi;
    while ((bi + 1) * NB - (bi + 1) * bi / 2 <= t0) ++bi;
    const int bj = bi + (t0 - (bi * NB - bi * (bi - 1) / 2));
    const int row0 = bi * 128;
    const int col0 = bj * 128;
    const bool diag = (bi == bj);

    if (tid < 128) { rsum[tid] = 0.f; csum[tid] = 0.f; }

    const int wr = wid >> 2;    // 0..1 : 64-row band
    const int wc = wid & 3;     // 0..3 : 32-col band
    f32x4 acc[4][2] = {};

    // staging: wave wid covers rows [wid*16, wid*16+16) of the 128x32 tile.
    // lane -> row = wid*16 + (lane>>2), chunkpos = lane&3;
    // source chunk = (lane&3) ^ ((row>>1)&3) = (lane&3) ^ ((lane>>3)&3)
    const int srow = wid * 16 + (lane >> 2);
    const int skc  = ((lane & 3) ^ ((lane >> 3) & 3)) * 8;
    const unsigned short* gA = z + (size_t)(row0 + srow) * D_DIM + skc;
    const unsigned short* gB = z + (size_t)(col0 + srow) * D_DIM + skc;

    const int kqi = lane >> 4;         // desired global k-chunk
    const int ml  = lane & 15;
    const int sw  = (ml >> 1) & 3;     // swizzle term for this row parity
    const int slot = (kqi ^ sw) * 8;

    auto stage = [&](int buf, int kt) {
        const int k0 = kt * 32;
        gl_lds16(gA + k0, &As[buf][(wid * 16) * 32]);
        gl_lds16(gB + k0, &Bs[buf][(wid * 16) * 32]);
    };
    auto compute = [&](int buf) {
        bf16x8 af[4], bfr[2];
        #pragma unroll
        for (int mi = 0; mi < 4; ++mi)
            af[mi] = *(const bf16x8*)&As[buf][(wr * 64 + mi * 16 + ml) * 32 + slot];
        #pragma unroll
        for (int ni = 0; ni < 2; ++ni)
            bfr[ni] = *(const bf16x8*)&Bs[buf][(wc * 32 + ni * 16 + ml) * 32 + slot];
        #pragma unroll
        for (int mi = 0; mi < 4; ++mi)
            #pragma unroll
            for (int ni = 0; ni < 2; ++ni)
                acc[mi][ni] = __builtin_amdgcn_mfma_f32_16x16x32_bf16(
                    af[mi], bfr[ni], acc[mi][ni], 0, 0, 0);
    };

    // prologue: three tiles in flight
    stage(0, 0); stage(1, 1); stage(2, 2);

    for (int kt = 0; kt < KT_N - 2; ++kt) {
        VM_WAIT(4);          // tile kt landed; kt+1, kt+2 still flying
        BAR();
        compute(kt % 3);
        LGKM0();             // all ds_reads of buf kt%3 retired
        BAR();
        if (kt + 3 < KT_N) stage(kt % 3, kt + 3);
    }
    {   // kt = KT_N-2: only tile KT_N-1 still flying (2 ops)
        VM_WAIT(2);
        BAR();
        compute((KT_N - 2) % 3);
        LGKM0();
        BAR();
    }
    {   // kt = KT_N-1: drain
        VM_WAIT(0);
        BAR();
        compute((KT_N - 1) % 3);
    }

    // epilogue: e = exp(2*sim), mask diagonal; row sums always, col sums if off-diag
    const int quad = lane >> 4;
    const int cl   = lane & 15;
    float colacc[2] = {0.f, 0.f};
    #pragma unroll
    for (int mi = 0; mi < 4; ++mi) {
        #pragma unroll
        for (int r = 0; r < 4; ++r) {
            const int lrow = wr * 64 + mi * 16 + quad * 4 + r;
            const int irow = row0 + lrow;
            float s = 0.f;
            #pragma unroll
            for (int ni = 0; ni < 2; ++ni) {
                const int jcol = col0 + wc * 32 + ni * 16 + cl;
                float e = __expf(TEMP_INV * acc[mi][ni][r]);
                e = (irow == jcol) ? 0.f : e;
                s += e;
                colacc[ni] += e;
            }
            s += __shfl_xor(s, 1);
            s += __shfl_xor(s, 2);
            s += __shfl_xor(s, 4);
            s += __shfl_xor(s, 8);
            if (cl == 0) atomicAdd(&rsum[lrow], s);
        }
    }
    if (!diag) {
        #pragma unroll
        for (int ni = 0; ni < 2; ++ni) {
            float c = colacc[ni];
            c += __shfl_xor(c, 16);
            c += __shfl_xor(c, 32);
            if (quad == 0) atomicAdd(&csum[wc * 32 + ni * 16 + cl], c);
        }
    }
    __syncthreads();
    if (tid < 128) {
        atomicAdd(&rowsum[row0 + tid], rsum[tid]);
        if (!diag) atomicAdd(&rowsum[col0 + tid], csum[tid]);
    }
}

// ---------------- kernel 3: finalize scalar loss ----------------
__global__ __launch_bounds__(256) void finalize_kernel(
    const float* __restrict__ rowsum, const float* __restrict__ pos,
    float* __restrict__ out) {
    const int t = threadIdx.x;
    float s = 0.f;
    for (int i = t; i < N_TOT; i += 256) s += logf(rowsum[i]);
    float p = 0.f;
    for (int i = t; i < B_ROWS; i += 256) p += pos[i];
    #pragma unroll
    for (int m = 32; m >= 1; m >>= 1) {
        s += __shfl_xor(s, m);
        p += __shfl_xor(p, m);
    }
    __shared__ float ws[4], wp[4];
    if ((t & 63) == 0) { ws[t >> 6] = s; wp[t >> 6] = p; }
    __syncthreads();
    if (t == 0) {
        float tot = ws[0] + ws[1] + ws[2] + ws[3];
        float ptot = wp[0] + wp[1] + wp[2] + wp[3];
        // loss = mean(log denom) - (2*posSum)/(temp*N)
        out[0] = tot / (float)N_TOT - ptot * (2.0f * TEMP_INV / (float)N_TOT);
    }
}

extern "C" void kernel_launch(void* const* d_in, const int* in_sizes, int n_in,
                              void* d_out, int out_size, void* d_ws, size_t ws_size,
                              hipStream_t stream) {
    const float* xi = (const float*)d_in[0];
    const float* xj = (const float*)d_in[1];
    float* out = (float*)d_out;
    char* ws = (char*)d_ws;

    unsigned short* z = (unsigned short*)ws;                       // 8 MB bf16
    float* rowsum = (float*)(ws + (size_t)N_TOT * D_DIM * 2);      // 32 KB
    float* pos = rowsum + N_TOT;                                   // 16 KB

    normpos_kernel<<<B_ROWS / 4, 256, 0, stream>>>(xi, xj, z, pos, rowsum);
    simrow_kernel<<<NTRI, 512, 0, stream>>>(z, rowsum);
    finalize_kernel<<<1, 256, 0, stream>>>(rowsum, pos, out);
}